// Round 8
// baseline (2069.735 us; speedup 1.0000x reference)
//
#include <hip/hip_runtime.h>

#define HH 64
#define TT 2048
#define BB 256
#define YSZ (BB*TT)   // y elements before hT in d_out

__device__ __forceinline__ float sigmoid_f(float v) {
    return 1.0f / (1.0f + __expf(-v));
}
__device__ __forceinline__ float tanh_f(float v) {
    return 1.0f - 2.0f / (1.0f + __expf(2.0f * v));
}

// AGPR-resident weights (R7-proven): v_accvgpr_write at init pins each weight
// in the (otherwise empty) AGPR class -- non-rematerializable, zero cache
// traffic; v_accvgpr_read + fma per MAC in the loop.
#define AW(dst, val)  asm("v_accvgpr_write_b32 %0, %1" : "=a"(dst) : "v"(val))
#define AR(dst, src)  asm("v_accvgpr_read_b32 %0, %1"  : "=v"(dst) : "a"(src))
#define AMAC(acc, w, h) { float _t_; AR(_t_, w); acc = fmaf(_t_, (h), acc); }

// R8 remap: gate thread (t = tid>>2 row 0..191, q = tid&3 k-quarter) -- the 4
// k-quarter partials of a row sit in adjacent lanes of one wave, reduced with
// 2 shfl_xor per accumulator (no LDS round-trip). Phase-B combine reads drop
// 24->6 (layer-1), 12->3 (layer-0), 4->1 (head).
// 1024 threads = 16 waves (4/SIMD):
//   waves 0-11 : gate rows (192 rows x 4 quarters)
//   waves 12-15: head rows (64 rows x 4 quarters)
//   phase B    : wave0 = layer-1 combine, wave1 = layer-0 combine,
//                wave2 = head finish (SIMDs 0/1/2)
__global__ __launch_bounds__(1024, 4)
void gru_fused(const float* __restrict__ x,      // [B,T,1]
               const float* __restrict__ h0in,   // [2,B,H]
               const float* __restrict__ W_ih0,  // [192,1]
               const float* __restrict__ W_hh0,  // [192,64]
               const float* __restrict__ b_ih0,  // [192]
               const float* __restrict__ b_hh0,  // [192]
               const float* __restrict__ W_ih1,  // [192,64]
               const float* __restrict__ W_hh1,  // [192,64]
               const float* __restrict__ b_ih1,  // [192]
               const float* __restrict__ b_hh1,  // [192]
               const float* __restrict__ Wh1,    // [64,64]
               const float* __restrict__ bh1,    // [64]
               const float* __restrict__ Wh2,    // [1,64]
               const float* __restrict__ bh2,    // [1]
               float* __restrict__ out)          // y [B*T] ++ hT [2,B,H]
{
    const int b   = blockIdx.x;
    const int tid = threadIdx.x;

    __shared__ __align__(16) float h0_lds[HH];
    __shared__ __align__(16) float h1_lds[HH];
    // reduced row sums, planar, padded stride 200 (banks spread, <=2-way)
    __shared__ __align__(16) float gbuf[3 * 200]; // plane0=gh0 plane1=gx1 plane2=gh1
    __shared__ __align__(16) float ph[HH];        // head row sums
    __shared__ __align__(16) float x_lds[TT];

    // ---- preload x row (coalesced float4), init h ----
    {
        const float4* xs = reinterpret_cast<const float4*>(x + (size_t)b * TT);
        float4*       xd = reinterpret_cast<float4*>(x_lds);
        if (tid < TT / 4) xd[tid] = xs[tid];
    }
    if (tid < HH) {
        h0_lds[tid] = h0in[          b * HH + tid];
        h1_lds[tid] = h0in[BB * HH + b * HH + tid];
    }

    // ---- role decode ----
    const bool is_gate = tid < 768;
    const int  q = tid & 3;                            // k-quarter 0..3
    const int  t = is_gate ? (tid >> 2) : ((tid - 768) >> 2); // row

    // ---- per-thread weight slices -> AGPRs (16 floats per matrix) ----
    float wA0x,wA0y,wA0z,wA0w, wA1x,wA1y,wA1z,wA1w,
          wA2x,wA2y,wA2z,wA2w, wA3x,wA3y,wA3z,wA3w;
    float wB0x,wB0y,wB0z,wB0w, wB1x,wB1y,wB1z,wB1w,
          wB2x,wB2y,wB2z,wB2w, wB3x,wB3y,wB3z,wB3w;
    float wC0x,wC0y,wC0z,wC0w, wC1x,wC1y,wC1z,wC1w,
          wC2x,wC2y,wC2z,wC2w, wC3x,wC3y,wC3z,wC3w;

#define LOADM(P, ptr) { const float4* _p4 = reinterpret_cast<const float4*>(ptr); \
    float4 f4; \
    f4 = _p4[0]; AW(P##0x, f4.x); AW(P##0y, f4.y); AW(P##0z, f4.z); AW(P##0w, f4.w); \
    f4 = _p4[1]; AW(P##1x, f4.x); AW(P##1y, f4.y); AW(P##1z, f4.z); AW(P##1w, f4.w); \
    f4 = _p4[2]; AW(P##2x, f4.x); AW(P##2y, f4.y); AW(P##2z, f4.z); AW(P##2w, f4.w); \
    f4 = _p4[3]; AW(P##3x, f4.x); AW(P##3y, f4.y); AW(P##3z, f4.z); AW(P##3w, f4.w); }

    if (is_gate) {
        LOADM(wA, W_hh0 + t * HH + q * 16);
        LOADM(wB, W_ih1 + t * HH + q * 16);
        LOADM(wC, W_hh1 + t * HH + q * 16);
    } else {
        LOADM(wA, Wh1 + t * HH + q * 16);
    }

    // ---- phase-B constants (combine waves; biases moved out of AGPRs) ----
    // wave 0: layer-1 combine consts
    float bxr = 0.f, bxz = 0.f, bxn = 0.f, bhr = 0.f, bhz = 0.f, bhn = 0.f;
    if (tid < 64) {
        const int j = tid;
        bxr = b_ih1[j]; bxz = b_ih1[j + 64]; bxn = b_ih1[j + 128];
        bhr = b_hh1[j]; bhz = b_hh1[j + 64]; bhn = b_hh1[j + 128];
    }
    // wave 1: layer-0 combine consts
    float wih0_r = 0.f, wih0_z = 0.f, wih0_n = 0.f;
    float bih0_r = 0.f, bih0_z = 0.f, bih0_n = 0.f;
    float bh0r = 0.f, bh0z = 0.f, bh0n = 0.f;
    if (tid >= 64 && tid < 128) {
        const int j = tid - 64;
        wih0_r = W_ih0[j];       bih0_r = b_ih0[j];
        wih0_z = W_ih0[j + 64];  bih0_z = b_ih0[j + 64];
        wih0_n = W_ih0[j + 128]; bih0_n = b_ih0[j + 128];
        bh0r = b_hh0[j]; bh0z = b_hh0[j + 64]; bh0n = b_hh0[j + 128];
    }
    // wave 2: head finish consts
    float wh2r = 0.f, bh1r = 0.f, bh2s = 0.f;
    if (tid >= 128 && tid < 192) {
        const int j = tid - 128;
        wh2r = Wh2[j]; bh1r = bh1[j]; bh2s = bh2[0];
    }

    __syncthreads();

    const float4* h0q = reinterpret_cast<const float4*>(h0_lds) + (q << 2);
    const float4* h1q = reinterpret_cast<const float4*>(h1_lds) + (q << 2);

    // gate step for float4-chunk j: 12 MACs, weights read from AGPR
#define GQ(j) { float4 u = h0q[j]; float4 v = h1q[j]; \
    AMAC(a0, wA##j##x, u.x); AMAC(a1, wB##j##x, u.x); AMAC(a2, wC##j##x, v.x); \
    AMAC(a0, wA##j##y, u.y); AMAC(a1, wB##j##y, u.y); AMAC(a2, wC##j##y, v.y); \
    AMAC(a0, wA##j##z, u.z); AMAC(a1, wB##j##z, u.z); AMAC(a2, wC##j##z, v.z); \
    AMAC(a0, wA##j##w, u.w); AMAC(a1, wB##j##w, u.w); AMAC(a2, wC##j##w, v.w); }
#define HQ(j) { float4 v = h1q[j]; \
    AMAC(s, wA##j##x, v.x); AMAC(s, wA##j##y, v.y); \
    AMAC(s, wA##j##z, v.z); AMAC(s, wA##j##w, v.w); }

    // Pipeline, 2 barriers/iter (schedule identical to rounds 1-7):
    //   A(i): partial gh0(i)=W_hh0@h0^i ; gx1(i-1)=W_ih1@h0^i ;
    //         gh1(i-1)=W_hh1@h1^(i-1) ; head partial from h1^(i-1)
    //   B(i): combine layer-1 -> h1^i ; combine layer-0 -> h0^(i+1) ; y[i-2]
    for (int i = 0; i <= TT + 1; ++i) {
        // ---------------- Phase A: quad-partial dots + shfl reduce ----------
        if (is_gate) {
            float a0 = 0.f, a1 = 0.f, a2 = 0.f;
            GQ(0) GQ(1) GQ(2) GQ(3)
            a0 += __shfl_xor(a0, 1, 64); a0 += __shfl_xor(a0, 2, 64);
            a1 += __shfl_xor(a1, 1, 64); a1 += __shfl_xor(a1, 2, 64);
            a2 += __shfl_xor(a2, 1, 64); a2 += __shfl_xor(a2, 2, 64);
            if (q < 3) {
                float v = (q == 0) ? a0 : (q == 1) ? a1 : a2;
                gbuf[q * 200 + t] = v;   // <=2-way bank overlap (free)
            }
        } else {
            float s = 0.f;
            HQ(0) HQ(1) HQ(2) HQ(3)
            s += __shfl_xor(s, 1, 64); s += __shfl_xor(s, 2, 64);
            if (q == 0) ph[t] = s;
        }
        __syncthreads();

        // ---------------- Phase B: combines ----------------
        if (tid < 64) {
            // layer-1 combine for step (i-1): 6 LDS reads
            const int j = tid;
            float xr = gbuf[200 + j]       + bxr;
            float xz = gbuf[200 + j + 64]  + bxz;
            float xn = gbuf[200 + j + 128] + bxn;
            float hr = gbuf[400 + j]       + bhr;
            float hz = gbuf[400 + j + 64]  + bhz;
            float hn = gbuf[400 + j + 128] + bhn;
            float r = sigmoid_f(xr + hr);
            float z = sigmoid_f(xz + hz);
            float n = tanh_f(fmaf(r, hn, xn));
            if (i >= 1 && i <= TT) {
                float hp = h1_lds[j];
                h1_lds[j] = fmaf(z, hp - n, n);   // (1-z)*n + z*h
            }
        } else if (tid < 128) {
            // layer-0 combine for step i: 3 LDS reads
            const int j  = tid - 64;
            const int xi = (i < TT) ? i : (TT - 1);
            float g0 = gbuf[j]       + bh0r;
            float g1 = gbuf[j + 64]  + bh0z;
            float g2 = gbuf[j + 128] + bh0n;
            float xv = x_lds[xi];
            float r = sigmoid_f(fmaf(xv, wih0_r, bih0_r) + g0);
            float z = sigmoid_f(fmaf(xv, wih0_z, bih0_z) + g1);
            float n = tanh_f(fmaf(r, g2, fmaf(xv, wih0_n, bih0_n)));
            if (i < TT) {
                float hp = h0_lds[j];
                h0_lds[j] = fmaf(z, hp - n, n);
            }
        } else if (tid < 192) {
            // head finish for y[i-2]: 1 LDS read + wave reduce
            const int j = tid - 128;
            float s = ph[j] + bh1r;
            float p = fmaxf(s, 0.f) * wh2r;
            #pragma unroll
            for (int m = 1; m < 64; m <<= 1) p += __shfl_xor(p, m, 64);
            if (tid == 128 && i >= 2) out[(size_t)b * TT + (i - 2)] = p + bh2s;
        }
        __syncthreads();
    }

    // final hidden states: hT[2,B,H]
    if (tid < HH) {
        out[YSZ +           b * HH + tid] = h0_lds[tid];
        out[YSZ + BB * HH + b * HH + tid] = h1_lds[tid];
    }
}

extern "C" void kernel_launch(void* const* d_in, const int* in_sizes, int n_in,
                              void* d_out, int out_size, void* d_ws, size_t ws_size,
                              hipStream_t stream) {
    const float* x     = (const float*)d_in[0];
    const float* h0in  = (const float*)d_in[1];
    const float* W_ih0 = (const float*)d_in[2];
    const float* W_hh0 = (const float*)d_in[3];
    const float* b_ih0 = (const float*)d_in[4];
    const float* b_hh0 = (const float*)d_in[5];
    const float* W_ih1 = (const float*)d_in[6];
    const float* W_hh1 = (const float*)d_in[7];
    const float* b_ih1 = (const float*)d_in[8];
    const float* b_hh1 = (const float*)d_in[9];
    const float* Wh1   = (const float*)d_in[10];
    const float* bh1   = (const float*)d_in[11];
    const float* Wh2   = (const float*)d_in[12];
    const float* bh2   = (const float*)d_in[13];
    float* out = (float*)d_out;

    gru_fused<<<dim3(BB), dim3(1024), 0, stream>>>(
        x, h0in, W_ih0, W_hh0, b_ih0, b_hh0,
        W_ih1, W_hh1, b_ih1, b_hh1, Wh1, bh1, Wh2, bh2, out);
}